// Round 14
// baseline (408.752 us; speedup 1.0000x reference)
//
#include <hip/hip_runtime.h>
#include <hip/hip_bf16.h>
#include <math.h>

// Problem constants (fixed by the reference file).
constexpr int N = 100000;     // nodes
constexpr int E = 1000000;    // edges
constexpr int D = 64;         // feature dim

__device__ __forceinline__ ushort f2bf(float x) {  // round-to-nearest-even bf16
  const unsigned u = __float_as_uint(x);
  return (ushort)((u + 0x7FFFu + ((u >> 16) & 1u)) >> 16);
}
__device__ __forceinline__ float bf2f(ushort u) {
  return __uint_as_float(((unsigned)u) << 16);
}

// ---------------------------------------------------------------------------
// Kernel 1: fused dual GEMM (+ in-degree histogram in the tail).
//   h2      = bf16(feat @ Wm + bm)      -> ws (gather reads 128B rows)
//   out_pre = a * (feat @ Wn + bn)      -> d_out (gather adds the rest)
// ---------------------------------------------------------------------------
__global__ __launch_bounds__(256) void node_gemm_hist(
    const float* __restrict__ feat,
    const float* __restrict__ Wn, const float* __restrict__ bn,
    const float* __restrict__ Wm, const float* __restrict__ bm,
    const float* __restrict__ alpha, const int* __restrict__ dst,
    ushort* __restrict__ h2, float* __restrict__ out_pre,
    int* __restrict__ cnt) {
  __shared__ float sWn[D * D];
  __shared__ float sWm[D * D];
  __shared__ float sF[64 * D];

  const int t = threadIdx.x;

  {
    const float4* Wn4 = reinterpret_cast<const float4*>(Wn);
    const float4* Wm4 = reinterpret_cast<const float4*>(Wm);
    float4* sWn4 = reinterpret_cast<float4*>(sWn);
    float4* sWm4 = reinterpret_cast<float4*>(sWm);
#pragma unroll
    for (int i = 0; i < 4; ++i) {
      sWn4[t + i * 256] = Wn4[t + i * 256];
      sWm4[t + i * 256] = Wm4[t + i * 256];
    }
  }
  const int row0 = blockIdx.x * 64;
  {
    float4* sF4 = reinterpret_cast<float4*>(sF);
    const float4* feat4 = reinterpret_cast<const float4*>(feat);
#pragma unroll
    for (int i = 0; i < 4; ++i) {
      const int idx = t + i * 256;   // 0..1023
      const int r = idx >> 4;        // tile row 0..63
      const int c4 = idx & 15;       // float4 column group
      const int gr = row0 + r;
      float4 v = make_float4(0.f, 0.f, 0.f, 0.f);
      if (gr < N) v = feat4[gr * 16 + c4];
      sF4[idx] = v;
    }
  }
  __syncthreads();

  const float a = 1.f / (1.f + __expf(-alpha[0]));
  const int d = t & 63;
  const int rg = t >> 6;  // wave id -> rows rg*16 .. rg*16+15

  float accN[16], accM[16];
#pragma unroll
  for (int j = 0; j < 16; ++j) { accN[j] = 0.f; accM[j] = 0.f; }

  for (int k4 = 0; k4 < 16; ++k4) {
    float wn[4], wm[4];
#pragma unroll
    for (int q = 0; q < 4; ++q) {
      wn[q] = sWn[(k4 * 4 + q) * D + d];
      wm[q] = sWm[(k4 * 4 + q) * D + d];
    }
#pragma unroll
    for (int j = 0; j < 16; ++j) {
      const float4 f = *reinterpret_cast<const float4*>(&sF[(rg * 16 + j) * D + k4 * 4]);
      accN[j] = fmaf(f.x, wn[0], accN[j]);
      accN[j] = fmaf(f.y, wn[1], accN[j]);
      accN[j] = fmaf(f.z, wn[2], accN[j]);
      accN[j] = fmaf(f.w, wn[3], accN[j]);
      accM[j] = fmaf(f.x, wm[0], accM[j]);
      accM[j] = fmaf(f.y, wm[1], accM[j]);
      accM[j] = fmaf(f.z, wm[2], accM[j]);
      accM[j] = fmaf(f.w, wm[3], accM[j]);
    }
  }

  const float bnd = bn[d];
  const float bmd = bm[d];
#pragma unroll
  for (int j = 0; j < 16; ++j) {
    const int gr = row0 + rg * 16 + j;
    if (gr < N) {
      h2[(size_t)gr * D + d] = f2bf(accM[j] + bmd);
      out_pre[(size_t)gr * D + d] = a * (accN[j] + bnd);
    }
  }

  // --- fused histogram tail ---
  const int stride = gridDim.x * 256;
  for (int e = blockIdx.x * 256 + t; e < E; e += stride)
    atomicAdd(&cnt[dst[e]], 1);
}

// ---------------------------------------------------------------------------
// Kernel 2: CSR row allocation (unsorted segments; one atomic per wave).
// ---------------------------------------------------------------------------
__global__ __launch_bounds__(256) void alloc_rows(const int* __restrict__ cnt,
                                                  int* __restrict__ gcur,
                                                  int* __restrict__ rowptr,
                                                  int* __restrict__ cursor) {
  const int v = blockIdx.x * 256 + threadIdx.x;
  const int lane = threadIdx.x & 63;
  const int c = (v < N) ? cnt[v] : 0;
  int incl = c;
#pragma unroll
  for (int off = 1; off < 64; off <<= 1) {
    const int y = __shfl_up(incl, off, 64);
    if (lane >= off) incl += y;
  }
  int base = 0;
  if (lane == 63) base = atomicAdd(gcur, incl);
  base = __shfl(base, 63, 64);
  if (v < N) {
    const int p = base + incl - c;
    rowptr[v] = p;
    cursor[v] = p;
  }
}

// ---------------------------------------------------------------------------
// Kernel 3: fill packed (src, attn_bits) per dst segment.
// ---------------------------------------------------------------------------
__global__ __launch_bounds__(256) void edge_fill(const int* __restrict__ src,
                                                 const int* __restrict__ dst,
                                                 const float* __restrict__ attn,
                                                 int* __restrict__ cursor,
                                                 int2* __restrict__ csr) {
  const int e = blockIdx.x * 256 + threadIdx.x;
  if (e < E) {
    const int v = dst[e];
    const int pos = atomicAdd(&cursor[v], 1);
    csr[pos] = make_int2(src[e], __float_as_int(attn[e]));
  }
}

// ---------------------------------------------------------------------------
// Kernel 4: quarter-wave gather. 16 lanes x ushort4 cover one 128B bf16
// h-row, so ONE wave-load fetches 4 edges' rows (one per quarter).
// 4 independent chains -> 16 edges in flight per wave; a deg~10 node
// completes in ~one csr->h2 latency round-trip (was ~3 dependent ones).
// 4 nodes/wave. Quarters folded by shfl_xor butterfly (masks 16, 32).
// ---------------------------------------------------------------------------
__global__ __launch_bounds__(256) void gather_combine(
    const ushort* __restrict__ h2, const int* __restrict__ rowptr,
    const int* __restrict__ cnt, const int2* __restrict__ csr,
    const float* __restrict__ alpha,
    float* __restrict__ out_pre, float* __restrict__ sums) {
  const int t = threadIdx.x;
  const int lane = t & 63;
  const int w = t >> 6;
  const int q = lane >> 4;    // quarter 0..3 -> which edge of the chunk
  const int lq = lane & 15;   // lane-in-quarter -> features lq*4 .. lq*4+3
  const float a = 1.f / (1.f + __expf(-alpha[0]));
  const float oma = 1.f - a;

  float4 psum = make_float4(0.f, 0.f, 0.f, 0.f);
  float4 psq  = make_float4(0.f, 0.f, 0.f, 0.f);

  const int vbase = blockIdx.x * 16 + w * 4;   // grid covers N exactly
#pragma unroll 1
  for (int j = 0; j < 4; ++j) {
    const int v = vbase + j;
    const int beg = rowptr[v];
    const int n = cnt[v];
    const int end = beg + n;

    float4 ac0 = make_float4(0.f, 0.f, 0.f, 0.f);
    float4 ac1 = make_float4(0.f, 0.f, 0.f, 0.f);
    float4 ac2 = make_float4(0.f, 0.f, 0.f, 0.f);
    float4 ac3 = make_float4(0.f, 0.f, 0.f, 0.f);

#pragma unroll 1
    for (int base = beg; base < end; base += 16) {
      // chain c handles edge base + c*4 + q  (16 edges per iteration)
#define CHAIN(AC, C)                                                          \
      {                                                                       \
        const int idx = base + (C) * 4 + q;                                   \
        const bool valid = idx < end;                                         \
        const int2 e = csr[valid ? idx : beg];                                \
        const float aw = valid ? __int_as_float(e.y) : 0.f;                   \
        const ushort4 hv = *reinterpret_cast<const ushort4*>(                 \
            h2 + (size_t)e.x * D + lq * 4);                                   \
        AC.x = fmaf(aw, bf2f(hv.x), AC.x);                                    \
        AC.y = fmaf(aw, bf2f(hv.y), AC.y);                                    \
        AC.z = fmaf(aw, bf2f(hv.z), AC.z);                                    \
        AC.w = fmaf(aw, bf2f(hv.w), AC.w);                                    \
      }
      CHAIN(ac0, 0)
      CHAIN(ac1, 1)
      CHAIN(ac2, 2)
      CHAIN(ac3, 3)
#undef CHAIN
    }

    // fold chains, then fold quarters (butterfly over lane bits 4,5)
    float4 fa;
    fa.x = (ac0.x + ac1.x) + (ac2.x + ac3.x);
    fa.y = (ac0.y + ac1.y) + (ac2.y + ac3.y);
    fa.z = (ac0.z + ac1.z) + (ac2.z + ac3.z);
    fa.w = (ac0.w + ac1.w) + (ac2.w + ac3.w);
#pragma unroll
    for (int mask = 16; mask <= 32; mask <<= 1) {
      fa.x += __shfl_xor(fa.x, mask, 64);
      fa.y += __shfl_xor(fa.y, mask, 64);
      fa.z += __shfl_xor(fa.z, mask, 64);
      fa.w += __shfl_xor(fa.w, mask, 64);
    }

    float4 cn;
    if (n > 0) {                         // wave-uniform branch
      cn = fa;
    } else {
      const ushort4 hv = *reinterpret_cast<const ushort4*>(
          h2 + (size_t)v * D + lq * 4);
      cn = make_float4(bf2f(hv.x), bf2f(hv.y), bf2f(hv.z), bf2f(hv.w));
    }

    if (q == 0) {                        // one quarter finalizes the node
      float4* op4 = reinterpret_cast<float4*>(out_pre) + (size_t)v * 16 + lq;
      float4 val = *op4;
      val.x = fmaf(oma, cn.x, val.x);
      val.y = fmaf(oma, cn.y, val.y);
      val.z = fmaf(oma, cn.z, val.z);
      val.w = fmaf(oma, cn.w, val.w);
      *op4 = val;
      psum.x += val.x; psum.y += val.y; psum.z += val.z; psum.w += val.w;
      psq.x = fmaf(val.x, val.x, psq.x);
      psq.y = fmaf(val.y, val.y, psq.y);
      psq.z = fmaf(val.z, val.z, psq.z);
      psq.w = fmaf(val.w, val.w, psq.w);
    }
  }

  __shared__ float sS[4][D];
  __shared__ float sQ[4][D];
  if (q == 0) {
    sS[w][lq * 4 + 0] = psum.x; sS[w][lq * 4 + 1] = psum.y;
    sS[w][lq * 4 + 2] = psum.z; sS[w][lq * 4 + 3] = psum.w;
    sQ[w][lq * 4 + 0] = psq.x;  sQ[w][lq * 4 + 1] = psq.y;
    sQ[w][lq * 4 + 2] = psq.z;  sQ[w][lq * 4 + 3] = psq.w;
  }
  __syncthreads();
  if (t < D) {
    const float s = (sS[0][t] + sS[1][t]) + (sS[2][t] + sS[3][t]);
    const float qq = (sQ[0][t] + sQ[1][t]) + (sQ[2][t] + sQ[3][t]);
    atomicAdd(&sums[t], s);
    atomicAdd(&sums[D + t], qq);
  }
}

// ---------------------------------------------------------------------------
// Kernel 5: normalize + ReLU with stats finalize inlined.
// ---------------------------------------------------------------------------
__global__ __launch_bounds__(256) void norm_relu(float* __restrict__ out,
                                                 const float* __restrict__ sums,
                                                 const float* __restrict__ gamma,
                                                 const float* __restrict__ beta) {
  __shared__ float sSc[D];
  __shared__ float sSh[D];
  const int t = threadIdx.x;
  if (t < D) {
    const float mean = sums[t] * (1.f / (float)N);
    const float var = (sums[D + t] - (float)N * mean * mean) / (float)(N - 1);
    const float rstd = 1.f / (sqrtf(var) + 1e-8f);
    const float sc = gamma[t] * rstd;
    sSc[t] = sc;
    sSh[t] = beta[t] - mean * sc;
  }
  __syncthreads();

  float4* out4 = reinterpret_cast<float4*>(out);
  const int total4 = N * D / 4;
  const int stride = gridDim.x * blockDim.x;   // multiple of 16 -> c fixed
  const int i0 = blockIdx.x * blockDim.x + t;
  const int c = i0 & 15;
  const float4 s = make_float4(sSc[c * 4], sSc[c * 4 + 1], sSc[c * 4 + 2], sSc[c * 4 + 3]);
  const float4 b = make_float4(sSh[c * 4], sSh[c * 4 + 1], sSh[c * 4 + 2], sSh[c * 4 + 3]);
  for (int i = i0; i < total4; i += stride) {
    float4 v = out4[i];
    v.x = fmaxf(fmaf(v.x, s.x, b.x), 0.f);
    v.y = fmaxf(fmaf(v.y, s.y, b.y), 0.f);
    v.z = fmaxf(fmaf(v.z, s.z, b.z), 0.f);
    v.w = fmaxf(fmaf(v.w, s.w, b.w), 0.f);
    out4[i] = v;
  }
}

extern "C" void kernel_launch(void* const* d_in, const int* in_sizes, int n_in,
                              void* d_out, int out_size, void* d_ws, size_t ws_size,
                              hipStream_t stream) {
  const float* feat  = (const float*)d_in[0];
  const int*   src   = (const int*)d_in[1];
  const int*   dst   = (const int*)d_in[2];
  const float* attn  = (const float*)d_in[3];
  const float* Wn    = (const float*)d_in[4];
  const float* bn    = (const float*)d_in[5];
  const float* Wm    = (const float*)d_in[6];
  const float* bm    = (const float*)d_in[7];
  const float* alpha = (const float*)d_in[8];
  const float* gamma = (const float*)d_in[9];
  const float* beta  = (const float*)d_in[10];

  float* out = (float*)d_out;

  // Workspace layout (~22 MB):
  ushort* h2     = (ushort*)d_ws;
  int*    cnt    = (int*)(h2 + (size_t)N * D);
  int*    gcur   = cnt + N;
  float*  sums   = (float*)(gcur + 32);
  int*    rowptr = (int*)(sums + 128);
  int*    cursor = rowptr + N;
  int2*   csr    = (int2*)(cursor + N);

  hipMemsetAsync(cnt, 0, (size_t)(N + 32 + 128) * sizeof(int), stream);

  node_gemm_hist<<<(N + 63) / 64, 256, 0, stream>>>(feat, Wn, bn, Wm, bm, alpha,
                                                    dst, h2, out, cnt);
  alloc_rows<<<(N + 255) / 256, 256, 0, stream>>>(cnt, gcur, rowptr, cursor);
  edge_fill<<<(E + 255) / 256, 256, 0, stream>>>(src, dst, attn, cursor, csr);
  gather_combine<<<N / 16, 256, 0, stream>>>(h2, rowptr, cnt, csr, alpha, out, sums);
  norm_relu<<<2048, 256, 0, stream>>>(out, sums, gamma, beta);
}

// Round 17
// 381.700 us; speedup vs baseline: 1.0709x; 1.0709x over previous
//
#include <hip/hip_runtime.h>
#include <hip/hip_bf16.h>
#include <math.h>

// Problem constants (fixed by the reference file).
constexpr int N = 100000;     // nodes
constexpr int E = 1000000;    // edges
constexpr int D = 64;         // feature dim

__device__ __forceinline__ ushort f2bf(float x) {  // round-to-nearest-even bf16
  const unsigned u = __float_as_uint(x);
  return (ushort)((u + 0x7FFFu + ((u >> 16) & 1u)) >> 16);
}
__device__ __forceinline__ float bf2f(ushort u) {
  return __uint_as_float(((unsigned)u) << 16);
}

// ---------------------------------------------------------------------------
// Kernel 1: fused dual GEMM (+ in-degree histogram in the tail).
//   h2      = bf16(feat @ Wm + bm)      -> ws (gather reads 128B rows)
//   out_pre = a * (feat @ Wn + bn)      -> d_out (gather adds the rest)
// ---------------------------------------------------------------------------
__global__ __launch_bounds__(256) void node_gemm_hist(
    const float* __restrict__ feat,
    const float* __restrict__ Wn, const float* __restrict__ bn,
    const float* __restrict__ Wm, const float* __restrict__ bm,
    const float* __restrict__ alpha, const int* __restrict__ dst,
    ushort* __restrict__ h2, float* __restrict__ out_pre,
    int* __restrict__ cnt) {
  __shared__ float sWn[D * D];
  __shared__ float sWm[D * D];
  __shared__ float sF[64 * D];

  const int t = threadIdx.x;

  {
    const float4* Wn4 = reinterpret_cast<const float4*>(Wn);
    const float4* Wm4 = reinterpret_cast<const float4*>(Wm);
    float4* sWn4 = reinterpret_cast<float4*>(sWn);
    float4* sWm4 = reinterpret_cast<float4*>(sWm);
#pragma unroll
    for (int i = 0; i < 4; ++i) {
      sWn4[t + i * 256] = Wn4[t + i * 256];
      sWm4[t + i * 256] = Wm4[t + i * 256];
    }
  }
  const int row0 = blockIdx.x * 64;
  {
    float4* sF4 = reinterpret_cast<float4*>(sF);
    const float4* feat4 = reinterpret_cast<const float4*>(feat);
#pragma unroll
    for (int i = 0; i < 4; ++i) {
      const int idx = t + i * 256;   // 0..1023
      const int r = idx >> 4;        // tile row 0..63
      const int c4 = idx & 15;       // float4 column group
      const int gr = row0 + r;
      float4 v = make_float4(0.f, 0.f, 0.f, 0.f);
      if (gr < N) v = feat4[gr * 16 + c4];
      sF4[idx] = v;
    }
  }
  __syncthreads();

  const float a = 1.f / (1.f + __expf(-alpha[0]));
  const int d = t & 63;
  const int rg = t >> 6;  // wave id -> rows rg*16 .. rg*16+15

  float accN[16], accM[16];
#pragma unroll
  for (int j = 0; j < 16; ++j) { accN[j] = 0.f; accM[j] = 0.f; }

  for (int k4 = 0; k4 < 16; ++k4) {
    float wn[4], wm[4];
#pragma unroll
    for (int q = 0; q < 4; ++q) {
      wn[q] = sWn[(k4 * 4 + q) * D + d];
      wm[q] = sWm[(k4 * 4 + q) * D + d];
    }
#pragma unroll
    for (int j = 0; j < 16; ++j) {
      const float4 f = *reinterpret_cast<const float4*>(&sF[(rg * 16 + j) * D + k4 * 4]);
      accN[j] = fmaf(f.x, wn[0], accN[j]);
      accN[j] = fmaf(f.y, wn[1], accN[j]);
      accN[j] = fmaf(f.z, wn[2], accN[j]);
      accN[j] = fmaf(f.w, wn[3], accN[j]);
      accM[j] = fmaf(f.x, wm[0], accM[j]);
      accM[j] = fmaf(f.y, wm[1], accM[j]);
      accM[j] = fmaf(f.z, wm[2], accM[j]);
      accM[j] = fmaf(f.w, wm[3], accM[j]);
    }
  }

  const float bnd = bn[d];
  const float bmd = bm[d];
#pragma unroll
  for (int j = 0; j < 16; ++j) {
    const int gr = row0 + rg * 16 + j;
    if (gr < N) {
      h2[(size_t)gr * D + d] = f2bf(accM[j] + bmd);
      out_pre[(size_t)gr * D + d] = a * (accN[j] + bnd);
    }
  }

  // --- fused histogram tail ---
  const int stride = gridDim.x * 256;
  for (int e = blockIdx.x * 256 + t; e < E; e += stride)
    atomicAdd(&cnt[dst[e]], 1);
}

// ---------------------------------------------------------------------------
// Kernel 2: CSR row allocation (unsorted segments; one atomic per wave).
// ---------------------------------------------------------------------------
__global__ __launch_bounds__(256) void alloc_rows(const int* __restrict__ cnt,
                                                  int* __restrict__ gcur,
                                                  int* __restrict__ rowptr,
                                                  int* __restrict__ cursor) {
  const int v = blockIdx.x * 256 + threadIdx.x;
  const int lane = threadIdx.x & 63;
  const int c = (v < N) ? cnt[v] : 0;
  int incl = c;
#pragma unroll
  for (int off = 1; off < 64; off <<= 1) {
    const int y = __shfl_up(incl, off, 64);
    if (lane >= off) incl += y;
  }
  int base = 0;
  if (lane == 63) base = atomicAdd(gcur, incl);
  base = __shfl(base, 63, 64);
  if (v < N) {
    const int p = base + incl - c;
    rowptr[v] = p;
    cursor[v] = p;
  }
}

// ---------------------------------------------------------------------------
// Kernel 3: fill packed (src, attn_bits) per dst segment.
// ---------------------------------------------------------------------------
__global__ __launch_bounds__(256) void edge_fill(const int* __restrict__ src,
                                                 const int* __restrict__ dst,
                                                 const float* __restrict__ attn,
                                                 int* __restrict__ cursor,
                                                 int2* __restrict__ csr) {
  const int e = blockIdx.x * 256 + threadIdx.x;
  if (e < E) {
    const int v = dst[e];
    const int pos = atomicAdd(&cursor[v], 1);
    csr[pos] = make_int2(src[e], __float_as_int(attn[e]));
  }
}

// ---------------------------------------------------------------------------
// Kernel 4 (round-7 structure + 8 chains): gather + combine + column stats.
// One wave per 8 nodes, lane = feature (64-lane-coherent 128B row loads —
// round 14 showed divergent quarter-loads serialize in the coalescer).
// 8 independent FMA chains keep 8 coherent row-loads in flight per wave:
// a deg~10 node completes in ~2 dependent csr->h2 round-trips (was ~3).
// Masked slots (aw=0, addr=beg) handle the tail uniformly.
// ---------------------------------------------------------------------------
__global__ __launch_bounds__(256) void gather_combine(
    const ushort* __restrict__ h2, const int* __restrict__ rowptr,
    const int* __restrict__ cnt, const int2* __restrict__ csr,
    const float* __restrict__ alpha,
    float* __restrict__ out_pre, float* __restrict__ sums) {
  const int t = threadIdx.x;
  const int d = t & 63;
  const int w = t >> 6;
  const float a = 1.f / (1.f + __expf(-alpha[0]));
  const float oma = 1.f - a;

  float psum = 0.f, psq = 0.f;
  const int vbase = blockIdx.x * 32 + w * 8;   // grid covers N exactly
#pragma unroll 1
  for (int j = 0; j < 8; ++j) {
    const int v = vbase + j;
    const int beg = rowptr[v];
    const int n = cnt[v];
    const int end = beg + n;

    float ac0 = 0.f, ac1 = 0.f, ac2 = 0.f, ac3 = 0.f;
    float ac4 = 0.f, ac5 = 0.f, ac6 = 0.f, ac7 = 0.f;

#pragma unroll 1
    for (int base = beg; base < end; base += 8) {
#define CHAIN(AC, C)                                                          \
      {                                                                       \
        const int idx = base + (C);                                           \
        const bool valid = idx < end;                                         \
        const int2 e = csr[valid ? idx : beg];                                \
        const float aw = valid ? __int_as_float(e.y) : 0.f;                   \
        AC = fmaf(aw, bf2f(h2[(size_t)e.x * D + d]), AC);                     \
      }
      CHAIN(ac0, 0)
      CHAIN(ac1, 1)
      CHAIN(ac2, 2)
      CHAIN(ac3, 3)
      CHAIN(ac4, 4)
      CHAIN(ac5, 5)
      CHAIN(ac6, 6)
      CHAIN(ac7, 7)
#undef CHAIN
    }

    float cn;
    if (n > 0) {                      // wave-uniform branch
      cn = ((ac0 + ac1) + (ac2 + ac3)) + ((ac4 + ac5) + (ac6 + ac7));
    } else {
      cn = bf2f(h2[(size_t)v * D + d]);
    }
    const float val = out_pre[(size_t)v * D + d] + oma * cn;
    out_pre[(size_t)v * D + d] = val;
    psum += val;
    psq = fmaf(val, val, psq);
  }

  __shared__ float sS[4][D];
  __shared__ float sQ[4][D];
  sS[w][d] = psum;
  sQ[w][d] = psq;
  __syncthreads();
  if (t < D) {
    const float s = (sS[0][t] + sS[1][t]) + (sS[2][t] + sS[3][t]);
    const float q = (sQ[0][t] + sQ[1][t]) + (sQ[2][t] + sQ[3][t]);
    atomicAdd(&sums[t], s);
    atomicAdd(&sums[D + t], q);
  }
}

// ---------------------------------------------------------------------------
// Kernel 5: normalize + ReLU with stats finalize inlined.
// ---------------------------------------------------------------------------
__global__ __launch_bounds__(256) void norm_relu(float* __restrict__ out,
                                                 const float* __restrict__ sums,
                                                 const float* __restrict__ gamma,
                                                 const float* __restrict__ beta) {
  __shared__ float sSc[D];
  __shared__ float sSh[D];
  const int t = threadIdx.x;
  if (t < D) {
    const float mean = sums[t] * (1.f / (float)N);
    const float var = (sums[D + t] - (float)N * mean * mean) / (float)(N - 1);
    const float rstd = 1.f / (sqrtf(var) + 1e-8f);
    const float sc = gamma[t] * rstd;
    sSc[t] = sc;
    sSh[t] = beta[t] - mean * sc;
  }
  __syncthreads();

  float4* out4 = reinterpret_cast<float4*>(out);
  const int total4 = N * D / 4;
  const int stride = gridDim.x * blockDim.x;   // multiple of 16 -> c fixed
  const int i0 = blockIdx.x * blockDim.x + t;
  const int c = i0 & 15;
  const float4 s = make_float4(sSc[c * 4], sSc[c * 4 + 1], sSc[c * 4 + 2], sSc[c * 4 + 3]);
  const float4 b = make_float4(sSh[c * 4], sSh[c * 4 + 1], sSh[c * 4 + 2], sSh[c * 4 + 3]);
  for (int i = i0; i < total4; i += stride) {
    float4 v = out4[i];
    v.x = fmaxf(fmaf(v.x, s.x, b.x), 0.f);
    v.y = fmaxf(fmaf(v.y, s.y, b.y), 0.f);
    v.z = fmaxf(fmaf(v.z, s.z, b.z), 0.f);
    v.w = fmaxf(fmaf(v.w, s.w, b.w), 0.f);
    out4[i] = v;
  }
}

extern "C" void kernel_launch(void* const* d_in, const int* in_sizes, int n_in,
                              void* d_out, int out_size, void* d_ws, size_t ws_size,
                              hipStream_t stream) {
  const float* feat  = (const float*)d_in[0];
  const int*   src   = (const int*)d_in[1];
  const int*   dst   = (const int*)d_in[2];
  const float* attn  = (const float*)d_in[3];
  const float* Wn    = (const float*)d_in[4];
  const float* bn    = (const float*)d_in[5];
  const float* Wm    = (const float*)d_in[6];
  const float* bm    = (const float*)d_in[7];
  const float* alpha = (const float*)d_in[8];
  const float* gamma = (const float*)d_in[9];
  const float* beta  = (const float*)d_in[10];

  float* out = (float*)d_out;

  // Workspace layout (~22 MB):
  ushort* h2     = (ushort*)d_ws;
  int*    cnt    = (int*)(h2 + (size_t)N * D);
  int*    gcur   = cnt + N;
  float*  sums   = (float*)(gcur + 32);
  int*    rowptr = (int*)(sums + 128);
  int*    cursor = rowptr + N;
  int2*   csr    = (int2*)(cursor + N);

  hipMemsetAsync(cnt, 0, (size_t)(N + 32 + 128) * sizeof(int), stream);

  node_gemm_hist<<<(N + 63) / 64, 256, 0, stream>>>(feat, Wn, bn, Wm, bm, alpha,
                                                    dst, h2, out, cnt);
  alloc_rows<<<(N + 255) / 256, 256, 0, stream>>>(cnt, gcur, rowptr, cursor);
  edge_fill<<<(E + 255) / 256, 256, 0, stream>>>(src, dst, attn, cursor, csr);
  gather_combine<<<N / 32, 256, 0, stream>>>(h2, rowptr, cnt, csr, alpha, out, sums);
  norm_relu<<<2048, 256, 0, stream>>>(out, sums, gamma, beta);
}